// Round 14
// baseline (52.797 us; speedup 1.0000x reference)
//
#include <hip/hip_runtime.h>

typedef float f4 __attribute__((ext_vector_type(4)));
typedef unsigned long long u64;

#define NPGL 256     // nodes per graph
#define EPGL 2048    // edges per graph
#define HIDD 64
#define KKEEP 128
#define NTH 1024
#define RSTR 76      // padded row stride: 76 mod 32 = 12 -> 8 bank-offset classes
                     // (was 72 -> only 4 classes -> quad-span collisions at P=1/4)

__device__ __forceinline__ int ro(int n, int c) { return n * RSTR + c * 4; }

__global__ void __launch_bounds__(NTH)
asap_fused(const float* __restrict__ x, const int* __restrict__ ei,
           const float* __restrict__ W1, const float* __restrict__ b1,
           const float* __restrict__ linW, const float* __restrict__ linb,
           const float* __restrict__ attW, const float* __restrict__ attb,
           const float* __restrict__ le1W, const float* __restrict__ le1b,
           const float* __restrict__ le2W,
           const float* __restrict__ le3W, const float* __restrict__ le3b,
           const float* __restrict__ W2, const float* __restrict__ b2,
           float* __restrict__ out, int Etot)
{
  const int g = blockIdx.x;
  const int tid = threadIdx.x;

  __shared__ __align__(16) float buf[NPGL * RSTR];   // 76KB: x -> h' -> h1 -> xnew
  __shared__ __align__(16) float mskf[4096];         // 16KB: Imask/Rmask/conn/kept...
  __shared__ __align__(16) float esc[4096];          // 16KB: exp scores / partials
  __shared__ __align__(8) unsigned char csrc[4096];  // 4KB padded CSR src (by dst)
  __shared__ unsigned short rowstP[NPGL + 1];        // 8-padded row starts
  __shared__ int cnt[NPGL];                          // counts -> cursors -> deg
  __shared__ float dinv_[NPGL];                      // conv1 norm -> LEConv c3
  __shared__ float sA[NPGL], sB[NPGL];
  __shared__ float rsf[NPGL];                        // fitness
  __shared__ float u_[HIDD], wsum[HIDD];
  __shared__ int scanwP[4];
  __shared__ float c0s;

  u64* Imask = (u64*)mskf;                 // [1024] = 8KB
  u64* Rmask = ((u64*)mskf) + 1024;        // [512]  = 4KB
  u64* conn  = ((u64*)mskf) + 1536;        // [256]  = 2KB
  int*   kept = (int*)(mskf + 3584);       // [128]
  float* d2A  = mskf + 3712;               // [128]
  float* cA   = mskf + 3840;               // [128]

  const int ebase = g * EPGL;
  const int nbase = g * NPGL;

  // ---------------- Phase 0: zero, edge loads, counts, x stage ----------------
  ((u64*)mskf)[tid] = 0ull;                          // zero Imask
  if (tid < NPGL) { cnt[tid] = 0; ((u64*)mskf)[1536 + tid] = 0ull; }  // zero conn
  __syncthreads();

  int es[2], ed[2];
#pragma unroll
  for (int i = 0; i < 2; ++i) {
    const int e = tid + i * NTH;
    es[i] = ei[ebase + e] - nbase;
    ed[i] = ei[Etot + ebase + e] - nbase;
    atomicAdd(&cnt[ed[i]], 1);
  }
  // stage x -> buf (padded)
  {
    const f4* xg = (const f4*)(x + (size_t)nbase * HIDD);
#pragma unroll
    for (int ii = 0; ii < 4; ++ii) {
      const int i = tid + ii * NTH;
      *(f4*)&buf[ro(i >> 4, i & 15)] = xg[i];
    }
  }
  __syncthreads();

  int sP = 0, mU = 0;
  if (tid < NPGL) {                 // wave scan of padded sizes
    mU = cnt[tid];
    sP = (mU + 7) & ~7;
#pragma unroll
    for (int off = 1; off < 64; off <<= 1) {
      const int uP = __shfl_up(sP, off, 64);
      if ((tid & 63) >= off) sP += uP;
    }
    if ((tid & 63) == 63) scanwP[tid >> 6] = sP;
  }
  __syncthreads();
  if (tid < NPGL) {
    int aP = 0;
    const int w = tid >> 6;
    for (int ww = 0; ww < w; ++ww) aP += scanwP[ww];
    rowstP[tid + 1] = (unsigned short)(sP + aP);
    if (tid == 0) rowstP[0] = 0;
    cnt[tid] = 0;                   // reset to arrival cursor
    dinv_[tid] = rsqrtf((float)mU + 1.0f);
  }
  if (tid < HIDD) {                 // u = lin_W @ attW[:64]
    float a = 0.f;
    for (int f = 0; f < HIDD; ++f) a += linW[tid * HIDD + f] * attW[f];
    u_[tid] = a;
  }
  if (tid == 0) {
    float a = 0.f;
    for (int f = 0; f < HIDD; ++f) a += linb[f] * attW[f];
    c0s = a + attb[0];
  }
  __syncthreads();

  // scatter into padded CSR + Imask bits
#pragma unroll
  for (int i = 0; i < 2; ++i) {
    const int j = atomicAdd(&cnt[ed[i]], 1);
    csrc[(int)rowstP[ed[i]] + j] = (unsigned char)es[i];
  }
  if (tid < NPGL) atomicOr(&Imask[tid * 4 + (tid >> 6)], 1ull << (tid & 63));
#pragma unroll
  for (int i = 0; i < 2; ++i)
    atomicOr(&Imask[ed[i] * 4 + (es[i] >> 6)], 1ull << (es[i] & 63));
  __syncthreads();

  // pad-fill: pad slots get the node's OWN index (algebraically-valid pads:
  // seg-max no-op; agg/softmax/fitness corrected by closed-form pc terms)
  if (tid < NPGL) {
    const int p = rowstP[tid];
    for (int j = cnt[tid]; (j & 7) != 0; ++j) csrc[p + j] = (unsigned char)tid;
  }

  // ---------------- Phase 1: h' = dinv * (x @ W1) (x from LDS, W1 scalar) ----------------
  {
    const int wv = tid >> 6;
    const int r  = ((wv & 3) << 6) + (tid & 63);
    const int fc = __builtin_amdgcn_readfirstlane(wv >> 2);
    const float* __restrict__ Wg = W1 + fc * 16;
    f4 acc[4];
#pragma unroll
    for (int c = 0; c < 4; ++c) acc[c] = f4{0.f, 0.f, 0.f, 0.f};
#pragma unroll
    for (int p = 0; p < 4; ++p) {
      f4 xa[4];
#pragma unroll
      for (int c = 0; c < 4; ++c) xa[c] = *(const f4*)&buf[ro(r, p * 4 + c)];
#pragma unroll
      for (int kk = 0; kk < 16; ++kk) {
        const int k = p * 16 + kk;
        const float xv = ((const float*)xa)[kk];
        const float* __restrict__ Wk = Wg + k * HIDD;   // uniform -> s_load
#pragma unroll
        for (int c = 0; c < 4; ++c)
          acc[c] += xv * *(const f4*)(Wk + c * 4);
      }
    }
    const float dv = dinv_[r];
    __syncthreads();                // all x reads (and pad-fill) before overwrite
#pragma unroll
    for (int c = 0; c < 4; ++c) *(f4*)&buf[ro(r, fc * 4 + c)] = acc[c] * dv;
  }
  __syncthreads();

  // persistent per-thread node geometry (cheap scalars only)
  const int d = tid >> 2, hh = tid & 3;
  const int deg = cnt[d];
  const int p0 = rowstP[d];
  const int hb = hh * 4;
  const int pc = (8 - (deg & 7)) & 7;     // pad count
  const int nb8 = (deg + 7) >> 3;         // padded batches of 8

  // ---------------- Phase 2: h1 = relu(dd*(sum h' + self) + b1) + sB fold ----------------
  {
    const float dd = dinv_[d];
    const float scl = 1.0f - (float)pc;   // pad correction on self row
    f4 acc[4], acc2[4];
#pragma unroll
    for (int j = 0; j < 4; ++j) {
      acc[j] = scl * *(const f4*)&buf[d * RSTR + hb + j * 16];
      acc2[j] = f4{0.f, 0.f, 0.f, 0.f};
    }
    for (int b = 0; b < nb8; ++b) {
      const u64 bits = *(const u64*)(csrc + p0 + (b << 3));
#pragma unroll
      for (int t = 0; t < 8; ++t) {
        const int s = (int)((bits >> (8 * t)) & 255);
        const int base = s * RSTR + hb;
        if (t & 1) {
#pragma unroll
          for (int j = 0; j < 4; ++j) acc2[j] += *(const f4*)&buf[base + j * 16];
        } else {
#pragma unroll
          for (int j = 0; j < 4; ++j) acc[j] += *(const f4*)&buf[base + j * 16];
        }
      }
    }
    float sBp = 0.f;
#pragma unroll
    for (int j = 0; j < 4; ++j) {
      acc[j] = (acc[j] + acc2[j]) * dd + *(const f4*)&b1[4 * (hh + 4 * j)];
      acc[j] = __builtin_elementwise_max(acc[j], f4{0.f, 0.f, 0.f, 0.f});
      const f4 aw = *(const f4*)&attW[HIDD + 4 * (hh + 4 * j)];
      sBp += acc[j].x * aw.x + acc[j].y * aw.y + acc[j].z * aw.z + acc[j].w * aw.w;
    }
    sBp += __shfl_xor(sBp, 1); sBp += __shfl_xor(sBp, 2);
    if (hh == 0) sB[d] = sBp;
    __syncthreads();
#pragma unroll
    for (int j = 0; j < 4; ++j) *(f4*)&buf[d * RSTR + hb + j * 16] = acc[j];
  }
  __syncthreads();

  // ---------------- Phase 3+4+5: seg-max -> sA -> softmax -> xnew ----------------
  {
    f4 mx[4], mx2[4];
#pragma unroll
    for (int j = 0; j < 4; ++j) {
      mx[j] = *(const f4*)&buf[d * RSTR + hb + j * 16];
      mx2[j] = mx[j];
    }
    for (int b = 0; b < nb8; ++b) {       // pads read own row: max no-op
      const u64 bits = *(const u64*)(csrc + p0 + (b << 3));
#pragma unroll
      for (int t = 0; t < 8; ++t) {
        const int s = (int)((bits >> (8 * t)) & 255);
        const int base = s * RSTR + hb;
        if (t & 1) {
#pragma unroll
          for (int j = 0; j < 4; ++j)
            mx2[j] = __builtin_elementwise_max(mx2[j], *(const f4*)&buf[base + j * 16]);
        } else {
#pragma unroll
          for (int j = 0; j < 4; ++j)
            mx[j] = __builtin_elementwise_max(mx[j], *(const f4*)&buf[base + j * 16]);
        }
      }
    }
    float sAv = 0.f;
#pragma unroll
    for (int j = 0; j < 4; ++j) {
      mx[j] = __builtin_elementwise_max(mx[j], mx2[j]);
      const f4 uu = *(const f4*)&u_[4 * (hh + 4 * j)];
      sAv += mx[j].x * uu.x + mx[j].y * uu.y + mx[j].z * uu.z + mx[j].w * uu.w;
    }
    sAv += __shfl_xor(sAv, 1); sAv += __shfl_xor(sAv, 2);
    const float sa = c0s + sAv;

    // softmax (branch-free over padded degree; pads give e == esf exactly)
    const int degP = deg + pc;
    const float sBd = sB[d];
    float mxB = sBd;
    for (int t = hh; t < degP; t += 4) mxB = fmaxf(mxB, sB[csrc[p0 + t]]);
    mxB = fmaxf(mxB, __shfl_xor(mxB, 1));
    mxB = fmaxf(mxB, __shfl_xor(mxB, 2));
    float mxv = sa + mxB;
    mxv = mxv >= 0.f ? mxv : 0.2f * mxv;
    float sum = 0.f;
    for (int t = hh; t < degP; t += 4) {
      float sc = sa + sB[csrc[p0 + t]];
      sc = sc >= 0.f ? sc : 0.2f * sc;
      const float e = __expf(sc - mxv);
      esc[p0 + t] = e;
      sum += e;
    }
    sum += __shfl_xor(sum, 1); sum += __shfl_xor(sum, 2);
    float scS = sa + sBd;
    scS = scS >= 0.f ? scS : 0.2f * scS;
    const float esf = __expf(scS - mxv);
    sum -= (float)pc * esf;               // remove pad contributions
    const float rs = 1.0f / (esf + sum + 1e-16f);
    asm volatile("s_waitcnt lgkmcnt(0)" ::: "memory");   // quad's esc visible

    // weighted gather (branch-free; pads contribute esf*own, pre-subtracted)
    f4 a[4], a2[4];
    const float scl2 = esf * (1.0f - (float)pc);
#pragma unroll
    for (int j = 0; j < 4; ++j) {
      a[j] = scl2 * *(const f4*)&buf[d * RSTR + hb + j * 16];
      a2[j] = f4{0.f, 0.f, 0.f, 0.f};
    }
    for (int b = 0; b < nb8; ++b) {
      const u64 bits = *(const u64*)(csrc + p0 + (b << 3));
      const int base8 = b << 3;
#pragma unroll
      for (int t = 0; t < 8; ++t) {
        const int s = (int)((bits >> (8 * t)) & 255);
        const int base = s * RSTR + hb;
        const float e = esc[p0 + base8 + t];
        if (t & 1) {
#pragma unroll
          for (int j = 0; j < 4; ++j) a2[j] += e * *(const f4*)&buf[base + j * 16];
        } else {
#pragma unroll
          for (int j = 0; j < 4; ++j) a[j] += e * *(const f4*)&buf[base + j * 16];
        }
      }
    }
#pragma unroll
    for (int j = 0; j < 4; ++j) a[j] = (a[j] + a2[j]) * rs;
    __syncthreads();
#pragma unroll
    for (int j = 0; j < 4; ++j) *(f4*)&buf[d * RSTR + hb + j * 16] = a[j];
  }
  __syncthreads();

  // ---------------- Phase 6: LEConv dots + fitness ----------------
  {
    float av = 0.f, bv = 0.f, cv = 0.f;
#pragma unroll
    for (int j = 0; j < 4; ++j) {
      const int c = hh + 4 * j;
      const f4 v = *(const f4*)&buf[d * RSTR + hb + j * 16];
      const int k = c * 4;
      av += v.x * le1W[k] + v.y * le1W[k + 1] + v.z * le1W[k + 2] + v.w * le1W[k + 3];
      bv += v.x * le2W[k] + v.y * le2W[k + 1] + v.z * le2W[k + 2] + v.w * le2W[k + 3];
      cv += v.x * le3W[k] + v.y * le3W[k + 1] + v.z * le3W[k + 2] + v.w * le3W[k + 3];
    }
    av += __shfl_xor(av, 1); av += __shfl_xor(av, 2);
    bv += __shfl_xor(bv, 1); bv += __shfl_xor(bv, 2);
    cv += __shfl_xor(cv, 1); cv += __shfl_xor(cv, 2);
    if (hh == 0) {
      sA[d] = av + le1b[0];
      sB[d] = bv;
      dinv_[d] = cv + le3b[0];
    }
  }
  __syncthreads();
  {
    const int degP = deg + pc;
    float fp = 0.f;                       // branch-free padded edge-sum
    for (int t = hh; t < degP; t += 4) fp += sA[csrc[p0 + t]];
    fp += __shfl_xor(fp, 1); fp += __shfl_xor(fp, 2);
    if (hh == 0) {
      float f = sA[d] + (fp - (float)pc * sA[d]);
      f -= (float)(deg + 1) * sB[d];
      f += dinv_[d];
      float sg;
      if (f >= 0.f) sg = 1.f / (1.f + expf(-f));
      else { const float t2 = expf(f); sg = t2 / (1.f + t2); }
      rsf[d] = sg;
    }
  }
  __syncthreads();

  // ---------------- Phase 7: top-K by rank ----------------
  {
    const float fn = rsf[d];
    int r = 0;
    for (int m = hh * 64; m < hh * 64 + 64; ++m) {
      const float fm = rsf[m];
      r += ((fm > fn) || (fm == fn && m < d)) ? 1 : 0;
    }
    r += __shfl_xor(r, 1); r += __shfl_xor(r, 2);
    if (hh == 0 && r < KKEEP) kept[r] = d;
  }
  __syncthreads();

  // ---------------- Phase 9: Rmask / conn ----------------
  if (tid < KKEEP * 4) {
    const int q = tid >> 2, w = tid & 3;
    const int kq = kept[q];
    u64 acc = 0ull;
#pragma unroll
    for (int ww = 0; ww < 4; ++ww) {
      u64 bits = Imask[kq * 4 + ww];
      while (bits) {
        const int m = (ww << 6) + __builtin_ctzll(bits);
        bits &= bits - 1;
        acc |= Imask[m * 4 + w];
      }
    }
    Rmask[q * 4 + w] = acc;
  }
  __syncthreads();
  if (tid < KKEEP * 4) {
    const int p = tid >> 2, wb = tid & 3;
    const int kp = kept[p];
    const u64 I0 = Imask[kp * 4 + 0], I1 = Imask[kp * 4 + 1],
              I2 = Imask[kp * 4 + 2], I3 = Imask[kp * 4 + 3];
    u64 bits = 0ull;
    for (int j = 0; j < 32; ++j) {
      const int q = wb * 32 + j;
      if (q == p) continue;
      const u64* R = &Rmask[q * 4];
      if ((I0 & R[0]) | (I1 & R[1]) | (I2 & R[2]) | (I3 & R[3]))
        bits |= 1ull << (q & 63);
    }
    atomicOr(&conn[p * 2 + (wb >> 1)], bits);
  }
  __syncthreads();

  // ---------------- Phase 10: deg2, d2, cA ----------------
  if (tid < KKEEP * 4) {
    const int q = tid >> 2, h = tid & 3;
    const int w = q >> 6, sh = q & 63;
    int c = 0;
    for (int p = h * 32; p < h * 32 + 32; ++p)
      c += (int)((conn[p * 2 + w] >> sh) & 1ull);
    c += __shfl_xor(c, 1); c += __shfl_xor(c, 2);
    if (h == 0) d2A[q] = rsqrtf((float)(c + 1));
  }
  __syncthreads();
  if (tid < KKEEP * 4) {
    const int s = tid >> 2, h = tid & 3;
    unsigned int b32 = (unsigned int)(conn[s * 2 + (h >> 1)] >> (32 * (h & 1)));
    const int base = ((h >> 1) << 6) + ((h & 1) << 5);
    float acc = 0.f;
    while (b32) {
      const int d_ = base + __builtin_ctz(b32);
      b32 &= b32 - 1;
      acc += d2A[d_];
    }
    acc += __shfl_xor(acc, 1); acc += __shfl_xor(acc, 2);
    if (h == 0)
      cA[s] = d2A[s] * (d2A[s] + acc) * rsf[kept[s]] * (1.0f / (float)KKEEP);
  }
  __syncthreads();

  // ---------------- Phase 11: wsum[k] = sum_s cA[s]*xnew[kept[s],k]; out ----------------
  {
    const int f = tid & 63, blk = tid >> 6;   // 16 blocks of 8 kept nodes
    float p = 0.f;
    for (int j = 0; j < 8; ++j) {
      const int s = blk * 8 + j;
      const int ks = kept[s];
      p += cA[s] * buf[ks * RSTR + f];        // consecutive lanes: conflict-free
    }
    esc[blk * 64 + f] = p;
  }
  __syncthreads();
  if (tid < HIDD) {
    float s = 0.f;
#pragma unroll
    for (int b = 0; b < 16; ++b) s += esc[b * 64 + tid];
    wsum[tid] = s;
  }
  __syncthreads();
  if (tid < HIDD) {
    float o = b2[tid];
    for (int k = 0; k < HIDD; ++k) o += wsum[k] * W2[k * HIDD + tid];
    out[(size_t)g * HIDD + tid] = o;
  }
}

extern "C" void kernel_launch(void* const* d_in, const int* in_sizes, int n_in,
                              void* d_out, int out_size, void* d_ws, size_t ws_size,
                              hipStream_t stream) {
  (void)n_in; (void)out_size; (void)d_ws; (void)ws_size;
  const float* x    = (const float*)d_in[0];
  const int*   ei   = (const int*)d_in[1];
  // d_in[2] = batch (contiguous equal graphs; unused)
  const float* W1   = (const float*)d_in[3];
  const float* b1   = (const float*)d_in[4];
  const float* linW = (const float*)d_in[5];
  const float* linb = (const float*)d_in[6];
  const float* attW = (const float*)d_in[7];
  const float* attb = (const float*)d_in[8];
  const float* le1W = (const float*)d_in[9];
  const float* le1b = (const float*)d_in[10];
  const float* le2W = (const float*)d_in[11];
  const float* le3W = (const float*)d_in[12];
  const float* le3b = (const float*)d_in[13];
  const float* W2   = (const float*)d_in[14];
  const float* b2   = (const float*)d_in[15];
  const int Etot = in_sizes[1] / 2;   // 524288
  const int nGraphs = 256;

  asap_fused<<<dim3(nGraphs), dim3(NTH), 0, stream>>>(
      x, ei, W1, b1, linW, linb, attW, attb, le1W, le1b, le2W, le3W, le3b,
      W2, b2, (float*)d_out, Etot);
}

// Round 15
// 51.215 us; speedup vs baseline: 1.0309x; 1.0309x over previous
//
#include <hip/hip_runtime.h>

typedef float f4 __attribute__((ext_vector_type(4)));
typedef unsigned long long u64;

#define NPGL 256     // nodes per graph
#define EPGL 2048    // edges per graph
#define HIDD 64
#define KKEEP 128
#define NTH 1024
#define RSTR 72      // padded row stride in floats

__device__ __forceinline__ int ro(int n, int c) { return n * RSTR + c * 4; }

__global__ void __launch_bounds__(NTH)
asap_fused(const float* __restrict__ x, const int* __restrict__ ei,
           const float* __restrict__ W1, const float* __restrict__ b1,
           const float* __restrict__ linW, const float* __restrict__ linb,
           const float* __restrict__ attW, const float* __restrict__ attb,
           const float* __restrict__ le1W, const float* __restrict__ le1b,
           const float* __restrict__ le2W,
           const float* __restrict__ le3W, const float* __restrict__ le3b,
           const float* __restrict__ W2, const float* __restrict__ b2,
           float* __restrict__ out, int Etot)
{
  const int g = blockIdx.x;
  const int tid = threadIdx.x;

  __shared__ __align__(16) float buf[NPGL * RSTR];   // 72KB: x -> h' -> h1 -> xnew
  __shared__ __align__(16) float mskf[4096];         // 16KB: Imask/Rmask/conn/kept...
  __shared__ __align__(16) float esc[1024];          // 4KB: ph11 partials only
  __shared__ __align__(8) unsigned char csrc[4096];  // 4KB padded CSR src (by dst)
  __shared__ unsigned short rowstP[NPGL + 1];        // 8-padded row starts
  __shared__ int cnt[NPGL];                          // counts -> cursors -> deg
  __shared__ float dinv_[NPGL];                      // conv1 norm -> LEConv c3
  __shared__ float sA[NPGL], sB[NPGL];
  __shared__ float rsf[NPGL];                        // fitness
  __shared__ float u_[HIDD], wsum[HIDD];
  __shared__ int scanwP[4];                          // scan scratch -> mxw (float)
  __shared__ float c0s;

  u64* Imask = (u64*)mskf;                 // [1024] = 8KB
  u64* Rmask = ((u64*)mskf) + 1024;        // [512]  = 4KB
  u64* conn  = ((u64*)mskf) + 1536;        // [256]  = 2KB
  int*   kept = (int*)(mskf + 3584);       // [128]
  float* d2A  = mskf + 3712;               // [128]
  float* cA   = mskf + 3840;               // [128]
  float* mxw  = (float*)scanwP;            // reuse after ph0

  const int ebase = g * EPGL;
  const int nbase = g * NPGL;

  // ---------------- Phase 0: zero, edge loads, counts, x stage ----------------
  ((u64*)mskf)[tid] = 0ull;                          // zero Imask
  if (tid < NPGL) { cnt[tid] = 0; ((u64*)mskf)[1536 + tid] = 0ull; }  // zero conn
  __syncthreads();

  int es[2], ed[2];
#pragma unroll
  for (int i = 0; i < 2; ++i) {
    const int e = tid + i * NTH;
    es[i] = ei[ebase + e] - nbase;
    ed[i] = ei[Etot + ebase + e] - nbase;
    atomicAdd(&cnt[ed[i]], 1);
  }
  // stage x -> buf (padded)
  {
    const f4* xg = (const f4*)(x + (size_t)nbase * HIDD);
#pragma unroll
    for (int ii = 0; ii < 4; ++ii) {
      const int i = tid + ii * NTH;
      *(f4*)&buf[ro(i >> 4, i & 15)] = xg[i];
    }
  }
  __syncthreads();

  int sP = 0, mU = 0;
  if (tid < NPGL) {                 // wave scan of padded sizes
    mU = cnt[tid];
    sP = (mU + 7) & ~7;
#pragma unroll
    for (int off = 1; off < 64; off <<= 1) {
      const int uP = __shfl_up(sP, off, 64);
      if ((tid & 63) >= off) sP += uP;
    }
    if ((tid & 63) == 63) scanwP[tid >> 6] = sP;
  }
  __syncthreads();
  if (tid < NPGL) {
    int aP = 0;
    const int w = tid >> 6;
    for (int ww = 0; ww < w; ++ww) aP += scanwP[ww];
    rowstP[tid + 1] = (unsigned short)(sP + aP);
    if (tid == 0) rowstP[0] = 0;
    cnt[tid] = 0;                   // reset to arrival cursor
    dinv_[tid] = rsqrtf((float)mU + 1.0f);
  }
  if (tid < HIDD) {                 // u = lin_W @ attW[:64]
    float a = 0.f;
    for (int f = 0; f < HIDD; ++f) a += linW[tid * HIDD + f] * attW[f];
    u_[tid] = a;
  }
  if (tid == 0) {
    float a = 0.f;
    for (int f = 0; f < HIDD; ++f) a += linb[f] * attW[f];
    c0s = a + attb[0];
  }
  __syncthreads();

  // scatter into padded CSR + Imask bits
#pragma unroll
  for (int i = 0; i < 2; ++i) {
    const int j = atomicAdd(&cnt[ed[i]], 1);
    csrc[(int)rowstP[ed[i]] + j] = (unsigned char)es[i];
  }
  if (tid < NPGL) atomicOr(&Imask[tid * 4 + (tid >> 6)], 1ull << (tid & 63));
#pragma unroll
  for (int i = 0; i < 2; ++i)
    atomicOr(&Imask[ed[i] * 4 + (es[i] >> 6)], 1ull << (es[i] & 63));
  __syncthreads();

  // pad-fill: pad slots get the node's OWN index (algebraically-valid pads)
  if (tid < NPGL) {
    const int p = rowstP[tid];
    for (int j = cnt[tid]; (j & 7) != 0; ++j) csrc[p + j] = (unsigned char)tid;
  }

  // ---------------- Phase 1: h' = dinv * (x @ W1) (x from LDS, W1 scalar) ----------------
  {
    const int wv = tid >> 6;
    const int r  = ((wv & 3) << 6) + (tid & 63);
    const int fc = __builtin_amdgcn_readfirstlane(wv >> 2);
    const float* __restrict__ Wg = W1 + fc * 16;
    f4 acc[4];
#pragma unroll
    for (int c = 0; c < 4; ++c) acc[c] = f4{0.f, 0.f, 0.f, 0.f};
#pragma unroll
    for (int p = 0; p < 4; ++p) {
      f4 xa[4];
#pragma unroll
      for (int c = 0; c < 4; ++c) xa[c] = *(const f4*)&buf[ro(r, p * 4 + c)];
#pragma unroll
      for (int kk = 0; kk < 16; ++kk) {
        const int k = p * 16 + kk;
        const float xv = ((const float*)xa)[kk];
        const float* __restrict__ Wk = Wg + k * HIDD;   // uniform -> s_load
#pragma unroll
        for (int c = 0; c < 4; ++c)
          acc[c] += xv * *(const f4*)(Wk + c * 4);
      }
    }
    const float dv = dinv_[r];
    __syncthreads();                // all x reads (and pad-fill) before overwrite
#pragma unroll
    for (int c = 0; c < 4; ++c) *(f4*)&buf[ro(r, fc * 4 + c)] = acc[c] * dv;
  }
  __syncthreads();

  // persistent per-thread node geometry (cheap scalars only)
  const int d = tid >> 2, hh = tid & 3;
  const int deg = cnt[d];
  const int p0 = rowstP[d];
  const int hb = hh * 4;
  const int pc = (8 - (deg & 7)) & 7;     // pad count
  const int nb8 = (deg + 7) >> 3;         // padded batches of 8

  // ---------------- Phase 2: h1 = relu(dd*(sum h' + self) + b1) + sB fold ----------------
  {
    const float dd = dinv_[d];
    const float scl = 1.0f - (float)pc;   // pad correction on self row
    f4 acc[4], acc2[4];
#pragma unroll
    for (int j = 0; j < 4; ++j) {
      acc[j] = scl * *(const f4*)&buf[d * RSTR + hb + j * 16];
      acc2[j] = f4{0.f, 0.f, 0.f, 0.f};
    }
    for (int b = 0; b < nb8; ++b) {
      const u64 bits = *(const u64*)(csrc + p0 + (b << 3));
#pragma unroll
      for (int t = 0; t < 8; ++t) {
        const int s = (int)((bits >> (8 * t)) & 255);
        const int base = s * RSTR + hb;
        if (t & 1) {
#pragma unroll
          for (int j = 0; j < 4; ++j) acc2[j] += *(const f4*)&buf[base + j * 16];
        } else {
#pragma unroll
          for (int j = 0; j < 4; ++j) acc[j] += *(const f4*)&buf[base + j * 16];
        }
      }
    }
    float sBp = 0.f;
#pragma unroll
    for (int j = 0; j < 4; ++j) {
      acc[j] = (acc[j] + acc2[j]) * dd + *(const f4*)&b1[4 * (hh + 4 * j)];
      acc[j] = __builtin_elementwise_max(acc[j], f4{0.f, 0.f, 0.f, 0.f});
      const f4 aw = *(const f4*)&attW[HIDD + 4 * (hh + 4 * j)];
      sBp += acc[j].x * aw.x + acc[j].y * aw.y + acc[j].z * aw.z + acc[j].w * aw.w;
    }
    sBp += __shfl_xor(sBp, 1); sBp += __shfl_xor(sBp, 2);
    if (hh == 0) sB[d] = sBp;
    __syncthreads();                // sB complete; buf reads done
    // block-wide max of sB (global softmax shift), piggybacked on this gap
    if (tid < NPGL) {
      float mg = sB[tid];
#pragma unroll
      for (int off = 1; off < 64; off <<= 1) mg = fmaxf(mg, __shfl_xor(mg, off, 64));
      if ((tid & 63) == 0) mxw[tid >> 6] = mg;
    }
#pragma unroll
    for (int j = 0; j < 4; ++j) *(f4*)&buf[d * RSTR + hb + j * 16] = acc[j];
  }
  __syncthreads();
  const float mxG = fmaxf(fmaxf(mxw[0], mxw[1]), fmaxf(mxw[2], mxw[3]));

  // ---------------- Phase 3+4+5: seg-max -> sA -> fused softmax+xnew ----------------
  {
    f4 mx[4], mx2[4];
#pragma unroll
    for (int j = 0; j < 4; ++j) {
      mx[j] = *(const f4*)&buf[d * RSTR + hb + j * 16];
      mx2[j] = mx[j];
    }
    for (int b = 0; b < nb8; ++b) {       // pads read own row: max no-op
      const u64 bits = *(const u64*)(csrc + p0 + (b << 3));
#pragma unroll
      for (int t = 0; t < 8; ++t) {
        const int s = (int)((bits >> (8 * t)) & 255);
        const int base = s * RSTR + hb;
        if (t & 1) {
#pragma unroll
          for (int j = 0; j < 4; ++j)
            mx2[j] = __builtin_elementwise_max(mx2[j], *(const f4*)&buf[base + j * 16]);
        } else {
#pragma unroll
          for (int j = 0; j < 4; ++j)
            mx[j] = __builtin_elementwise_max(mx[j], *(const f4*)&buf[base + j * 16]);
        }
      }
    }
    float sAv = 0.f;
#pragma unroll
    for (int j = 0; j < 4; ++j) {
      mx[j] = __builtin_elementwise_max(mx[j], mx2[j]);
      const f4 uu = *(const f4*)&u_[4 * (hh + 4 * j)];
      sAv += mx[j].x * uu.x + mx[j].y * uu.y + mx[j].z * uu.z + mx[j].w * uu.w;
    }
    sAv += __shfl_xor(sAv, 1); sAv += __shfl_xor(sAv, 2);
    const float sa = c0s + sAv;

    // global-shift softmax fused with weighted gather: one loop does
    // e-compute + sum + accumulation. All 4 quad lanes compute identical
    // e from a broadcast sB[s] read -> no cross-lane exchange needed.
    const float sBd = sB[d];
    float mxv = sa + mxG;                       // >= all scores of this node
    mxv = mxv >= 0.f ? mxv : 0.2f * mxv;
    float scS = sa + sBd;
    scS = scS >= 0.f ? scS : 0.2f * scS;
    const float esf = __expf(scS - mxv);

    f4 a[4], a2[4];
    const float scl2 = esf * (1.0f - (float)pc);
#pragma unroll
    for (int j = 0; j < 4; ++j) {
      a[j] = scl2 * *(const f4*)&buf[d * RSTR + hb + j * 16];
      a2[j] = f4{0.f, 0.f, 0.f, 0.f};
    }
    float sum = 0.f;
    for (int b = 0; b < nb8; ++b) {
      const u64 bits = *(const u64*)(csrc + p0 + (b << 3));
#pragma unroll
      for (int t = 0; t < 8; ++t) {
        const int s = (int)((bits >> (8 * t)) & 255);
        float sc = sa + sB[s];
        sc = sc >= 0.f ? sc : 0.2f * sc;
        const float e = __expf(sc - mxv);
        sum += e;
        const int base = s * RSTR + hb;
        if (t & 1) {
#pragma unroll
          for (int j = 0; j < 4; ++j) a2[j] += e * *(const f4*)&buf[base + j * 16];
        } else {
#pragma unroll
          for (int j = 0; j < 4; ++j) a[j] += e * *(const f4*)&buf[base + j * 16];
        }
      }
    }
    sum -= (float)pc * esf;                     // remove pad contributions
    const float rs = 1.0f / (esf + sum + 1e-16f);
#pragma unroll
    for (int j = 0; j < 4; ++j) a[j] = (a[j] + a2[j]) * rs;
    __syncthreads();
#pragma unroll
    for (int j = 0; j < 4; ++j) *(f4*)&buf[d * RSTR + hb + j * 16] = a[j];
  }
  __syncthreads();

  // ---------------- Phase 6: LEConv dots + fitness ----------------
  {
    float av = 0.f, bv = 0.f, cv = 0.f;
#pragma unroll
    for (int j = 0; j < 4; ++j) {
      const int c = hh + 4 * j;
      const f4 v = *(const f4*)&buf[d * RSTR + hb + j * 16];
      const int k = c * 4;
      av += v.x * le1W[k] + v.y * le1W[k + 1] + v.z * le1W[k + 2] + v.w * le1W[k + 3];
      bv += v.x * le2W[k] + v.y * le2W[k + 1] + v.z * le2W[k + 2] + v.w * le2W[k + 3];
      cv += v.x * le3W[k] + v.y * le3W[k + 1] + v.z * le3W[k + 2] + v.w * le3W[k + 3];
    }
    av += __shfl_xor(av, 1); av += __shfl_xor(av, 2);
    bv += __shfl_xor(bv, 1); bv += __shfl_xor(bv, 2);
    cv += __shfl_xor(cv, 1); cv += __shfl_xor(cv, 2);
    if (hh == 0) {
      sA[d] = av + le1b[0];
      sB[d] = bv;
      dinv_[d] = cv + le3b[0];
    }
  }
  __syncthreads();
  {
    const int degP = deg + pc;
    float fp = 0.f;                       // branch-free padded edge-sum
    for (int t = hh; t < degP; t += 4) fp += sA[csrc[p0 + t]];
    fp += __shfl_xor(fp, 1); fp += __shfl_xor(fp, 2);
    if (hh == 0) {
      float f = sA[d] + (fp - (float)pc * sA[d]);
      f -= (float)(deg + 1) * sB[d];
      f += dinv_[d];
      float sg;
      if (f >= 0.f) sg = 1.f / (1.f + expf(-f));
      else { const float t2 = expf(f); sg = t2 / (1.f + t2); }
      rsf[d] = sg;
    }
  }
  __syncthreads();

  // ---------------- Phase 7: top-K by rank ----------------
  {
    const float fn = rsf[d];
    int r = 0;
    for (int m = hh * 64; m < hh * 64 + 64; ++m) {
      const float fm = rsf[m];
      r += ((fm > fn) || (fm == fn && m < d)) ? 1 : 0;
    }
    r += __shfl_xor(r, 1); r += __shfl_xor(r, 2);
    if (hh == 0 && r < KKEEP) kept[r] = d;
  }
  __syncthreads();

  // ---------------- Phase 9: Rmask / conn ----------------
  if (tid < KKEEP * 4) {
    const int q = tid >> 2, w = tid & 3;
    const int kq = kept[q];
    u64 acc = 0ull;
#pragma unroll
    for (int ww = 0; ww < 4; ++ww) {
      u64 bits = Imask[kq * 4 + ww];
      while (bits) {
        const int m = (ww << 6) + __builtin_ctzll(bits);
        bits &= bits - 1;
        acc |= Imask[m * 4 + w];
      }
    }
    Rmask[q * 4 + w] = acc;
  }
  __syncthreads();
  if (tid < KKEEP * 4) {
    const int p = tid >> 2, wb = tid & 3;
    const int kp = kept[p];
    const u64 I0 = Imask[kp * 4 + 0], I1 = Imask[kp * 4 + 1],
              I2 = Imask[kp * 4 + 2], I3 = Imask[kp * 4 + 3];
    u64 bits = 0ull;
    for (int j = 0; j < 32; ++j) {
      const int q = wb * 32 + j;
      if (q == p) continue;
      const u64* R = &Rmask[q * 4];
      if ((I0 & R[0]) | (I1 & R[1]) | (I2 & R[2]) | (I3 & R[3]))
        bits |= 1ull << (q & 63);
    }
    atomicOr(&conn[p * 2 + (wb >> 1)], bits);
  }
  __syncthreads();

  // ---------------- Phase 10: deg2, d2, cA ----------------
  if (tid < KKEEP * 4) {
    const int q = tid >> 2, h = tid & 3;
    const int w = q >> 6, sh = q & 63;
    int c = 0;
    for (int p = h * 32; p < h * 32 + 32; ++p)
      c += (int)((conn[p * 2 + w] >> sh) & 1ull);
    c += __shfl_xor(c, 1); c += __shfl_xor(c, 2);
    if (h == 0) d2A[q] = rsqrtf((float)(c + 1));
  }
  __syncthreads();
  if (tid < KKEEP * 4) {
    const int s = tid >> 2, h = tid & 3;
    unsigned int b32 = (unsigned int)(conn[s * 2 + (h >> 1)] >> (32 * (h & 1)));
    const int base = ((h >> 1) << 6) + ((h & 1) << 5);
    float acc = 0.f;
    while (b32) {
      const int d_ = base + __builtin_ctz(b32);
      b32 &= b32 - 1;
      acc += d2A[d_];
    }
    acc += __shfl_xor(acc, 1); acc += __shfl_xor(acc, 2);
    if (h == 0)
      cA[s] = d2A[s] * (d2A[s] + acc) * rsf[kept[s]] * (1.0f / (float)KKEEP);
  }
  __syncthreads();

  // ---------------- Phase 11: wsum[k] = sum_s cA[s]*xnew[kept[s],k]; out ----------------
  {
    const int f = tid & 63, blk = tid >> 6;   // 16 blocks of 8 kept nodes
    float p = 0.f;
    for (int j = 0; j < 8; ++j) {
      const int s = blk * 8 + j;
      const int ks = kept[s];
      p += cA[s] * buf[ks * RSTR + f];        // consecutive lanes: conflict-free
    }
    esc[blk * 64 + f] = p;
  }
  __syncthreads();
  if (tid < HIDD) {
    float s = 0.f;
#pragma unroll
    for (int b = 0; b < 16; ++b) s += esc[b * 64 + tid];
    wsum[tid] = s;
  }
  __syncthreads();
  if (tid < HIDD) {
    float o = b2[tid];
    for (int k = 0; k < HIDD; ++k) o += wsum[k] * W2[k * HIDD + tid];
    out[(size_t)g * HIDD + tid] = o;
  }
}

extern "C" void kernel_launch(void* const* d_in, const int* in_sizes, int n_in,
                              void* d_out, int out_size, void* d_ws, size_t ws_size,
                              hipStream_t stream) {
  (void)n_in; (void)out_size; (void)d_ws; (void)ws_size;
  const float* x    = (const float*)d_in[0];
  const int*   ei   = (const int*)d_in[1];
  // d_in[2] = batch (contiguous equal graphs; unused)
  const float* W1   = (const float*)d_in[3];
  const float* b1   = (const float*)d_in[4];
  const float* linW = (const float*)d_in[5];
  const float* linb = (const float*)d_in[6];
  const float* attW = (const float*)d_in[7];
  const float* attb = (const float*)d_in[8];
  const float* le1W = (const float*)d_in[9];
  const float* le1b = (const float*)d_in[10];
  const float* le2W = (const float*)d_in[11];
  const float* le3W = (const float*)d_in[12];
  const float* le3b = (const float*)d_in[13];
  const float* W2   = (const float*)d_in[14];
  const float* b2   = (const float*)d_in[15];
  const int Etot = in_sizes[1] / 2;   // 524288
  const int nGraphs = 256;

  asap_fused<<<dim3(nGraphs), dim3(NTH), 0, stream>>>(
      x, ei, W1, b1, linW, linb, attW, attb, le1W, le1b, le2W, le3W, le3b,
      W2, b2, (float*)d_out, Etot);
}